// Round 18
// baseline (58.373 us; speedup 1.0000x reference)
//
#include <hip/hip_runtime.h>
#include <math.h>

// Exact pipeline (verified rounds 4-17, absmax=0): dot = ascending FMA chain,
// d = (x2 + dot') + e2 with e' = -2e folded (exact), strict-< first-occurrence.
// NEW: integer prescreen. q = rint(v*127) (inputs in [0,1)); screen metric
// M_k = 2*dot(qx,qe_k) - sum(qe_k^2)  == exact int32 via two chained sdot4.
// argmin d_hat == argmax M (qx^2 is row-constant). Bound: |d - d_hat/127^2|
// <= 8.0004/127  =>  every exact-argmin achiever has M >= Mmax - 2033.
// Groups flagged with running-max threshold (superset-safe); exact fp32
// re-score of flagged groups decides everything -> screen can only cost
// speed, never correctness.
#pragma clang fp contract(off)

constexpr int KCODES = 2048;   // EMBEDDING_LENGTH
constexpr int CDIM   = 4;      // EMBEDDING_DIM
constexpr int KSPLIT = 16;     // one k-chunk per wave
constexpr int KCHUNK = KCODES / KSPLIT;  // 128 codes per wave
constexpr int RPT    = 4;      // rows per lane
constexpr int ROWSPB = 64 * RPT;         // 256 rows per block
constexpr int TPB    = 64 * KSPLIT;      // 1024 threads
constexpr int NGROUP = KCHUNK / 8;       // 16 groups of 8 codes
constexpr int MARGIN = 2048;             // >= 2*eps_q = 2033 (proof in header)

__device__ __forceinline__ int dot4(int a, int b, int c) {
#if __has_builtin(__builtin_amdgcn_sdot4)
    return __builtin_amdgcn_sdot4(a, b, c, false);
#else
    int d; asm("v_dot4_i32_i8 %0, %1, %2, %3" : "=v"(d) : "v"(a), "v"(b), "v"(c));
    return d;
#endif
}

__global__ __launch_bounds__(TPB, 4) void vq_fused(
    const float* __restrict__ x,
    const float* __restrict__ emb,
    int* __restrict__ out,
    int N)
{
    // carve 56 KB: sE 32K (e'=-2e) | sS 8K (e2 flat) | sQE 8K | sNC 8K.
    // skey (34 KB) reuses the base after a barrier.
    __shared__ char smem[57344];
    float4*   sE  = reinterpret_cast<float4*>(smem);
    float*    sS  = reinterpret_cast<float*>(smem + 32768);
    unsigned* sQE = reinterpret_cast<unsigned*>(smem + 40960);
    int*      sNC = reinterpret_cast<int*>(smem + 49152);

    const float4* __restrict__ embf4 = reinterpret_cast<const float4*>(emb);
    const int t = threadIdx.x;

    for (int i = t; i < KCODES; i += TPB) {
        float4 e = embf4[i];
        sE[i] = make_float4(-2.0f * e.x, -2.0f * e.y, -2.0f * e.z, -2.0f * e.w);
        sS[i] = ((e.x * e.x + e.y * e.y) + e.z * e.z) + e.w * e.w;
        const int q0 = (int)rintf(e.x * 127.0f), q1 = (int)rintf(e.y * 127.0f);
        const int q2 = (int)rintf(e.z * 127.0f), q3 = (int)rintf(e.w * 127.0f);
        sQE[i] = (unsigned)(q0 | (q1 << 8) | (q2 << 16) | (q3 << 24));
        sNC[i] = -(q0 * q0 + q1 * q1 + q2 * q2 + q3 * q3);
    }
    __syncthreads();

    const int lane  = t & 63;
    const int wid   = __builtin_amdgcn_readfirstlane(t >> 6);  // r6 lesson
    const int kbase = wid * KCHUNK;
    const int nbase = blockIdx.x * ROWSPB + lane;

    float x0[RPT], x1[RPT], x2c[RPT], x3[RPT], xs[RPT];
    int   qxp[RPT], Mmax[RPT];
    unsigned gmask[RPT];
    #pragma unroll
    for (int r = 0; r < RPT; ++r) {
        const int n = nbase + r * 64;
        float4 xv = (n < N) ? reinterpret_cast<const float4*>(x)[n]
                            : make_float4(0.f, 0.f, 0.f, 0.f);
        x0[r] = xv.x; x1[r] = xv.y; x2c[r] = xv.z; x3[r] = xv.w;
        xs[r] = ((xv.x * xv.x + xv.y * xv.y) + xv.z * xv.z) + xv.w * xv.w;
        const int a0 = (int)rintf(xv.x * 127.0f), a1 = (int)rintf(xv.y * 127.0f);
        const int a2 = (int)rintf(xv.z * 127.0f), a3 = (int)rintf(xv.w * 127.0f);
        qxp[r] = a0 | (a1 << 8) | (a2 << 16) | (a3 << 24);
        Mmax[r] = (int)0x80000000;
        gmask[r] = 0u;
    }

    // ---- integer screen: 2 chained sdot4 per code, exact int32 ----
    #pragma unroll 2
    for (int g = 0; g < NGROUP; ++g) {
        const int k0 = kbase + (g << 3);
        const uint4 qa = *reinterpret_cast<const uint4*>(sQE + k0);
        const uint4 qb = *reinterpret_cast<const uint4*>(sQE + k0 + 4);
        const int4  na = *reinterpret_cast<const int4*>(sNC + k0);
        const int4  nb = *reinterpret_cast<const int4*>(sNC + k0 + 4);

        #pragma unroll
        for (int r = 0; r < RPT; ++r) {
            const int qx = qxp[r];
            const int M0 = dot4(qx, (int)qa.x, dot4(qx, (int)qa.x, na.x));
            const int M1 = dot4(qx, (int)qa.y, dot4(qx, (int)qa.y, na.y));
            const int M2 = dot4(qx, (int)qa.z, dot4(qx, (int)qa.z, na.z));
            const int M3 = dot4(qx, (int)qa.w, dot4(qx, (int)qa.w, na.w));
            const int M4 = dot4(qx, (int)qb.x, dot4(qx, (int)qb.x, nb.x));
            const int M5 = dot4(qx, (int)qb.y, dot4(qx, (int)qb.y, nb.y));
            const int M6 = dot4(qx, (int)qb.z, dot4(qx, (int)qb.z, nb.z));
            const int M7 = dot4(qx, (int)qb.w, dot4(qx, (int)qb.w, nb.w));
            const int gm = max(max(max(M0, M1), max(M2, M3)),
                               max(max(M4, M5), max(M6, M7)));
            const int Mm = max(Mmax[r], gm);
            Mmax[r] = Mm;
            // flagged iff group could contain an exact-min achiever
            // (running max <= final max -> superset of the true candidate set)
            gmask[r] |= (gm >= Mm - MARGIN) ? (1u << g) : 0u;
        }
    }

    // ---- exact fp32 re-score of flagged groups (bit-exact verified chain),
    // ascending k + strict <  =>  np.argmin first-occurrence.
    unsigned long long key[RPT];
    #pragma unroll
    for (int r = 0; r < RPT; ++r) {
        const float a0 = x0[r], a1 = x1[r], a2 = x2c[r], a3 = x3[r];
        const float xq = xs[r];
        float dmin = HUGE_VALF;
        int   idx  = 0;
        unsigned m = gmask[r];
        while (m) {
            const int g = __builtin_ctz(m);
            m &= m - 1;
            const int k0 = kbase + (g << 3);
            #pragma unroll
            for (int j = 0; j < 8; ++j) {
                const int k = k0 + j;
                const float4 e = sE[k];
                float dt = a0 * e.x;
                dt = __builtin_fmaf(a1, e.y, dt);
                dt = __builtin_fmaf(a2, e.z, dt);
                dt = __builtin_fmaf(a3, e.w, dt);
                const float d = (xq + dt) + sS[k];
                if (d < dmin) { dmin = d; idx = k; }
            }
        }
        // d >= 0 for this data: float bits order-isomorphic as u32; low bits
        // break exact cross-wave ties toward the smaller index.
        key[r] = ((unsigned long long)__float_as_uint(dmin) << 32)
                 | (unsigned)idx;
    }

    // ---- cross-wave reduce: reuse smem (256 x 17 u64 = 34 KB) ----
    __syncthreads();
    unsigned long long* skey = reinterpret_cast<unsigned long long*>(smem);
    #pragma unroll
    for (int r = 0; r < RPT; ++r)
        skey[(r * 64 + lane) * (KSPLIT + 1) + wid] = key[r];
    __syncthreads();

    if (t < ROWSPB) {
        const int rn = blockIdx.x * ROWSPB + t;
        if (rn < N) {
            unsigned long long k = skey[t * (KSPLIT + 1)];
            #pragma unroll
            for (int s = 1; s < KSPLIT; ++s) {
                unsigned long long v = skey[t * (KSPLIT + 1) + s];
                if (v < k) k = v;
            }
            out[rn] = (int)(unsigned)(k & 0xFFFFFFFFull);
        }
    }
}

extern "C" void kernel_launch(void* const* d_in, const int* in_sizes, int n_in,
                              void* d_out, int out_size, void* d_ws, size_t ws_size,
                              hipStream_t stream) {
    const float* x   = (const float*)d_in[0];   // [16,64,64,4] -> [N,4]
    const float* emb = (const float*)d_in[1];   // [2048,4]
    int* out = (int*)d_out;                     // [N] int32
    const int N = in_sizes[0] / CDIM;           // 65536

    vq_fused<<<(N + ROWSPB - 1) / ROWSPB, TPB, 0, stream>>>(x, emb, out, N);
}

// Round 19
// 37.546 us; speedup vs baseline: 1.5547x; 1.5547x over previous
//
#include <hip/hip_runtime.h>
#include <math.h>

// Exact pipeline (verified rounds 4-18, absmax=0): dot = ascending FMA chain,
// d = (x2 + dot') + e2 with e' = -2e folded (exact), strict-< first-occurrence.
//
// r19: fp32 SCREEN with cheap association + exact re-score (r18's proven
// flag-and-rescore pattern, precision fixed). Screen:
//   dhat_k = fma(x0,e'0, fma(x1,e'1, fma(x2,e'2, fma(x3,e'3, s_k))))   (4 fma)
// Both dhat and (dexact - xs) approximate T = sum x_i e'_i + s_k with <= 6
// roundings on magnitudes <= 12 (ulp <= 1.9e-6) => |dhat - (dexact-xs)| <=
// ~9e-6; two-sided => any exact-argmin achiever's group-min screen value is
// within 1.8e-5 of the running screen min. MARGIN = 3e-5 (superset-safe;
// screen errors can only cost speed, never correctness). At 3e-5 vs typical
// top-2 gaps ~1e-3, flagged ~1 group/row (r18's failure was 0.127 margin).
#pragma clang fp contract(off)

constexpr int   KCODES = 2048;   // EMBEDDING_LENGTH
constexpr int   CDIM   = 4;      // EMBEDDING_DIM
constexpr int   KSPLIT = 16;     // one k-chunk per wave
constexpr int   KCHUNK = KCODES / KSPLIT;  // 128 codes per wave
constexpr int   RPT    = 4;      // rows per lane
constexpr int   ROWSPB = 64 * RPT;         // 256 rows per block
constexpr int   TPB    = 64 * KSPLIT;      // 1024 threads
constexpr int   NGROUP = KCHUNK / 8;       // 16 groups of 8 codes
constexpr float MARGIN = 3e-5f;  // > 2x screen-vs-exact bound (~1.8e-5)

__device__ __forceinline__ float min3f(float a, float b, float c) {
    float d; asm("v_min3_f32 %0, %1, %2, %3" : "=v"(d) : "v"(a), "v"(b), "v"(c)); return d;
}
__device__ __forceinline__ float sumsq(float4 e) {
    // np.sum(e*e, -1): ascending unfused mul-add (n<8 scalar loop)
    return ((e.x * e.x + e.y * e.y) + e.z * e.z) + e.w * e.w;
}

__global__ __launch_bounds__(TPB, 4) void vq_fused(
    const float* __restrict__ x,
    const float* __restrict__ emb,
    int* __restrict__ out,
    int N)
{
    // 40 KB: sE 32K (e' = -2e) | sS 8K (e2 sums, flat). skey (34K) reuses base.
    __shared__ char smem[40960];
    float4* sE = reinterpret_cast<float4*>(smem);           // [KCODES]
    float*  sS = reinterpret_cast<float*>(smem + 32768);    // [KCODES]

    const float4* __restrict__ embf4 = reinterpret_cast<const float4*>(emb);
    const int t = threadIdx.x;

    for (int i = t; i < KCODES; i += TPB) {
        float4 e = embf4[i];
        sE[i] = make_float4(-2.0f * e.x, -2.0f * e.y, -2.0f * e.z, -2.0f * e.w);
        sS[i] = sumsq(e);
    }
    __syncthreads();

    const int lane  = t & 63;
    const int wid   = __builtin_amdgcn_readfirstlane(t >> 6);  // r6 lesson
    const int kbase = wid * KCHUNK;
    const int nbase = blockIdx.x * ROWSPB + lane;

    float x0[RPT], x1[RPT], x2c[RPT], x3[RPT], xs[RPT];
    float rmin[RPT];
    unsigned gmask[RPT];
    #pragma unroll
    for (int r = 0; r < RPT; ++r) {
        const int n = nbase + r * 64;
        float4 xv = (n < N) ? reinterpret_cast<const float4*>(x)[n]
                            : make_float4(0.f, 0.f, 0.f, 0.f);
        x0[r] = xv.x; x1[r] = xv.y; x2c[r] = xv.z; x3[r] = xv.w;
        xs[r] = ((xv.x * xv.x + xv.y * xv.y) + xv.z * xv.z) + xv.w * xv.w;
        rmin[r] = HUGE_VALF; gmask[r] = 0u;
    }

    // ---- fp32 screen: 4 fma per code + group-min + flag ----
    #pragma unroll 2
    for (int g = 0; g < NGROUP; ++g) {
        const int k0 = kbase + (g << 3);
        const float4 e0 = sE[k0 + 0], e1 = sE[k0 + 1];
        const float4 e2 = sE[k0 + 2], e3 = sE[k0 + 3];
        const float4 e4 = sE[k0 + 4], e5 = sE[k0 + 5];
        const float4 e6 = sE[k0 + 6], e7 = sE[k0 + 7];
        const float4 sA = *reinterpret_cast<const float4*>(sS + k0);
        const float4 sB = *reinterpret_cast<const float4*>(sS + k0 + 4);

        #pragma unroll
        for (int r = 0; r < RPT; ++r) {
            const float a0 = x0[r], a1 = x1[r], a2 = x2c[r], a3 = x3[r];

            #define VQ_S(EV, SV, OUTV)                                    \
                do {                                                      \
                    float dh = __builtin_fmaf(a3, EV.w, SV);              \
                    dh = __builtin_fmaf(a2, EV.z, dh);                    \
                    dh = __builtin_fmaf(a1, EV.y, dh);                    \
                    OUTV = __builtin_fmaf(a0, EV.x, dh);                  \
                } while (0)

            float d0, d1, d2, d3, d4, d5, d6, d7;
            VQ_S(e0, sA.x, d0); VQ_S(e1, sA.y, d1);
            VQ_S(e2, sA.z, d2); VQ_S(e3, sA.w, d3);
            VQ_S(e4, sB.x, d4); VQ_S(e5, sB.y, d5);
            VQ_S(e6, sB.z, d6); VQ_S(e7, sB.w, d7);
            #undef VQ_S

            const float m1 = min3f(d0, d1, d2);
            const float m2 = min3f(d3, d4, d5);
            const float m3 = min3f(d6, d7, m1);
            const float gmin = fminf(m2, m3);
            const float rn2 = fminf(rmin[r], gmin);
            // flag iff this group could contain the exact argmin (superset:
            // running min >= final min, so the test only gets looser later)
            gmask[r] |= (gmin <= rn2 + MARGIN) ? (1u << g) : 0u;
            rmin[r] = rn2;
        }
    }

    // ---- exact re-score of flagged groups (bit-exact verified chain),
    // ascending g (ctz) + ascending j + strict <  =>  np.argmin first-occ.
    unsigned long long key[RPT];
    #pragma unroll
    for (int r = 0; r < RPT; ++r) {
        const float a0 = x0[r], a1 = x1[r], a2 = x2c[r], a3 = x3[r];
        const float xq = xs[r];
        float dmin = HUGE_VALF;
        int   idx  = 0;
        unsigned m = gmask[r];   // never empty: new-min group self-flags
        while (m) {
            const int g = __builtin_ctz(m);
            m &= m - 1;
            const int k0 = kbase + (g << 3);
            #pragma unroll
            for (int j = 0; j < 8; ++j) {
                const int k = k0 + j;
                const float4 e = sE[k];
                float dt = a0 * e.x;
                dt = __builtin_fmaf(a1, e.y, dt);
                dt = __builtin_fmaf(a2, e.z, dt);
                dt = __builtin_fmaf(a3, e.w, dt);
                const float d = (xq + dt) + sS[k];
                if (d < dmin) { dmin = d; idx = k; }
            }
        }
        // d >= 0 for this data: float bits order-isomorphic as u32; low bits
        // break exact cross-wave ties toward the smaller index.
        key[r] = ((unsigned long long)__float_as_uint(dmin) << 32)
                 | (unsigned)idx;
    }

    // ---- cross-wave reduce: reuse smem (256 x 17 u64 = 34 KB) ----
    __syncthreads();
    unsigned long long* skey = reinterpret_cast<unsigned long long*>(smem);
    #pragma unroll
    for (int r = 0; r < RPT; ++r)
        skey[(r * 64 + lane) * (KSPLIT + 1) + wid] = key[r];
    __syncthreads();

    if (t < ROWSPB) {
        const int rn = blockIdx.x * ROWSPB + t;
        if (rn < N) {
            unsigned long long k = skey[t * (KSPLIT + 1)];
            #pragma unroll
            for (int s = 1; s < KSPLIT; ++s) {
                unsigned long long v = skey[t * (KSPLIT + 1) + s];
                if (v < k) k = v;
            }
            out[rn] = (int)(unsigned)(k & 0xFFFFFFFFull);
        }
    }
}

extern "C" void kernel_launch(void* const* d_in, const int* in_sizes, int n_in,
                              void* d_out, int out_size, void* d_ws, size_t ws_size,
                              hipStream_t stream) {
    const float* x   = (const float*)d_in[0];   // [16,64,64,4] -> [N,4]
    const float* emb = (const float*)d_in[1];   // [2048,4]
    int* out = (int*)d_out;                     // [N] int32
    const int N = in_sizes[0] / CDIM;           // 65536

    vq_fused<<<(N + ROWSPB - 1) / ROWSPB, TPB, 0, stream>>>(x, emb, out, N);
}

// Round 20
// 30.551 us; speedup vs baseline: 1.9107x; 1.2290x over previous
//
#include <hip/hip_runtime.h>
#include <math.h>

// Exact pipeline (verified rounds 4-19, absmax=0): dot = ascending FMA chain,
// d = (xq + dot') + e2 with e' = -2e folded (exact), strict-< first-occurrence.
//
// r20: two-pass screen. Pass 1 stores per-16-code-group screen mins
// (4-fma/code chain seeded with s). Pass 2 flags groups against the FINAL
// min + MARGIN (r19's defect: running-min flagging marks every record group,
// H(16)~3.4x overflag -> divergent-rescore blowup). |screen - (d_exact-xq)|
// <= ~1.1e-5 per side (<=6 roundings, partials <= 8, ulp 9.5e-7); MARGIN
// 3e-5 is superset-safe: all exact-argmin achievers' groups are flagged,
// so screen error can only cost speed, never correctness.
#pragma clang fp contract(off)

constexpr int   KCODES = 2048;   // EMBEDDING_LENGTH
constexpr int   CDIM   = 4;      // EMBEDDING_DIM
constexpr int   KSPLIT = 16;     // one k-chunk per wave
constexpr int   KCHUNK = KCODES / KSPLIT;  // 128 codes per wave
constexpr int   RPT    = 4;      // rows per lane
constexpr int   ROWSPB = 64 * RPT;         // 256 rows per block
constexpr int   TPB    = 64 * KSPLIT;      // 1024 threads
constexpr int   NSG    = 8;      // super-groups of 16 codes
constexpr float MARGIN = 3e-5f;  // > two-sided screen-vs-exact bound (~2.2e-5)

__device__ __forceinline__ float min3f(float a, float b, float c) {
    float d; asm("v_min3_f32 %0, %1, %2, %3" : "=v"(d) : "v"(a), "v"(b), "v"(c)); return d;
}
__device__ __forceinline__ float sumsq(float4 e) {
    // np.sum(e*e, -1): ascending unfused mul-add (n<8 scalar loop)
    return ((e.x * e.x + e.y * e.y) + e.z * e.z) + e.w * e.w;
}

__global__ __launch_bounds__(TPB, 4) void vq_fused(
    const float* __restrict__ x,
    const float* __restrict__ emb,
    int* __restrict__ out,
    int N)
{
    // 40 KB: sE 32K (e' = -2e) | sS 8K (e2 sums, flat). skey (34K) reuses base.
    __shared__ char smem[40960];
    float4* sE = reinterpret_cast<float4*>(smem);           // [KCODES]
    float*  sS = reinterpret_cast<float*>(smem + 32768);    // [KCODES]

    const float4* __restrict__ embf4 = reinterpret_cast<const float4*>(emb);
    const int t = threadIdx.x;

    for (int i = t; i < KCODES; i += TPB) {
        float4 e = embf4[i];
        sE[i] = make_float4(-2.0f * e.x, -2.0f * e.y, -2.0f * e.z, -2.0f * e.w);
        sS[i] = sumsq(e);
    }
    __syncthreads();

    const int lane  = t & 63;
    const int wid   = __builtin_amdgcn_readfirstlane(t >> 6);  // r6 lesson
    const int kbase = wid * KCHUNK;
    const int nbase = blockIdx.x * ROWSPB + lane;

    float x0[RPT], x1[RPT], x2c[RPT], x3[RPT], xs[RPT];
    float gm[RPT][NSG];   // per-16-code-group screen mins (pass 1 output)
    #pragma unroll
    for (int r = 0; r < RPT; ++r) {
        const int n = nbase + r * 64;
        float4 xv = (n < N) ? reinterpret_cast<const float4*>(x)[n]
                            : make_float4(0.f, 0.f, 0.f, 0.f);
        x0[r] = xv.x; x1[r] = xv.y; x2c[r] = xv.z; x3[r] = xv.w;
        xs[r] = ((xv.x * xv.x + xv.y * xv.y) + xv.z * xv.z) + xv.w * xv.w;
    }

    // ---- pass 1: screen all codes, store group mins (no flagging) ----
    #pragma unroll 2
    for (int g = 0; g < NSG; ++g) {
        const int k0 = kbase + (g << 4);
        #pragma unroll
        for (int half = 0; half < 2; ++half) {
            const int kh = k0 + half * 8;
            const float4 e0 = sE[kh + 0], e1 = sE[kh + 1];
            const float4 e2 = sE[kh + 2], e3 = sE[kh + 3];
            const float4 e4 = sE[kh + 4], e5 = sE[kh + 5];
            const float4 e6 = sE[kh + 6], e7 = sE[kh + 7];
            const float4 sA = *reinterpret_cast<const float4*>(sS + kh);
            const float4 sB = *reinterpret_cast<const float4*>(sS + kh + 4);

            #pragma unroll
            for (int r = 0; r < RPT; ++r) {
                const float a0 = x0[r], a1 = x1[r], a2 = x2c[r], a3 = x3[r];
                #define VQ_S(EV, SV, OUTV)                                \
                    do {                                                  \
                        float dh = __builtin_fmaf(a3, EV.w, SV);          \
                        dh = __builtin_fmaf(a2, EV.z, dh);                \
                        dh = __builtin_fmaf(a1, EV.y, dh);                \
                        OUTV = __builtin_fmaf(a0, EV.x, dh);              \
                    } while (0)
                float d0, d1, d2, d3, d4, d5, d6, d7;
                VQ_S(e0, sA.x, d0); VQ_S(e1, sA.y, d1);
                VQ_S(e2, sA.z, d2); VQ_S(e3, sA.w, d3);
                VQ_S(e4, sB.x, d4); VQ_S(e5, sB.y, d5);
                VQ_S(e6, sB.z, d6); VQ_S(e7, sB.w, d7);
                #undef VQ_S
                const float m1 = min3f(d0, d1, d2);
                const float m2 = min3f(d3, d4, d5);
                const float m3 = min3f(d6, d7, m1);
                const float hmin = fminf(m2, m3);
                gm[r][g] = (half == 0) ? hmin : fminf(gm[r][g], hmin);
            }
        }
    }

    // ---- pass 2: final min -> flags -> exact rescore of flagged groups ----
    unsigned long long key[RPT];
    #pragma unroll
    for (int r = 0; r < RPT; ++r) {
        const float f1 = min3f(gm[r][0], gm[r][1], gm[r][2]);
        const float f2 = min3f(gm[r][3], gm[r][4], gm[r][5]);
        const float f3 = min3f(gm[r][6], gm[r][7], f1);
        const float thr = fminf(f2, f3) + MARGIN;

        unsigned m = 0u;
        #pragma unroll
        for (int g = 0; g < NSG; ++g)
            m |= (gm[r][g] <= thr) ? (1u << g) : 0u;

        const float a0 = x0[r], a1 = x1[r], a2 = x2c[r], a3 = x3[r];
        const float xq = xs[r];
        float dmin = HUGE_VALF;
        int   idx  = 0;
        // never empty: the group achieving fmin self-flags.
        while (m) {
            const int g = __builtin_ctz(m);
            m &= m - 1;
            const int k0 = kbase + (g << 4);
            #pragma unroll
            for (int j = 0; j < 16; ++j) {
                const int k = k0 + j;
                const float4 e = sE[k];
                float dt = a0 * e.x;
                dt = __builtin_fmaf(a1, e.y, dt);
                dt = __builtin_fmaf(a2, e.z, dt);
                dt = __builtin_fmaf(a3, e.w, dt);
                const float d = (xq + dt) + sS[k];
                if (d < dmin) { dmin = d; idx = k; }  // strict <: first occ.
            }
        }
        // d >= 0 for this data: float bits order-isomorphic as u32; low bits
        // break exact cross-wave ties toward the smaller index.
        key[r] = ((unsigned long long)__float_as_uint(dmin) << 32)
                 | (unsigned)idx;
    }

    // ---- cross-wave reduce: reuse smem (256 x 17 u64 = 34 KB) ----
    __syncthreads();
    unsigned long long* skey = reinterpret_cast<unsigned long long*>(smem);
    #pragma unroll
    for (int r = 0; r < RPT; ++r)
        skey[(r * 64 + lane) * (KSPLIT + 1) + wid] = key[r];
    __syncthreads();

    if (t < ROWSPB) {
        const int rn = blockIdx.x * ROWSPB + t;
        if (rn < N) {
            unsigned long long k = skey[t * (KSPLIT + 1)];
            #pragma unroll
            for (int s = 1; s < KSPLIT; ++s) {
                unsigned long long v = skey[t * (KSPLIT + 1) + s];
                if (v < k) k = v;
            }
            out[rn] = (int)(unsigned)(k & 0xFFFFFFFFull);
        }
    }
}

extern "C" void kernel_launch(void* const* d_in, const int* in_sizes, int n_in,
                              void* d_out, int out_size, void* d_ws, size_t ws_size,
                              hipStream_t stream) {
    const float* x   = (const float*)d_in[0];   // [16,64,64,4] -> [N,4]
    const float* emb = (const float*)d_in[1];   // [2048,4]
    int* out = (int*)d_out;                     // [N] int32
    const int N = in_sizes[0] / CDIM;           // 65536

    vq_fused<<<(N + ROWSPB - 1) / ROWSPB, TPB, 0, stream>>>(x, emb, out, N);
}

// Round 21
// 27.353 us; speedup vs baseline: 2.1340x; 1.1169x over previous
//
#include <hip/hip_runtime.h>
#include <math.h>

// Bit-match the verified reference fp32 pipeline (rounds 4-17, absmax=0):
//   dot = ascending single-accumulator FMA chain
//   d   = (x2 - 2*dot) + e2, single roundings, strict-< first-occurrence argmin.
// -2 folded into the staged table (exact; verified r14).
//
// FINAL STRUCTURE (r17, session-best 27.2us): plain exact scan.
// Ceiling arithmetic: 134.2M pairs x 6.55 lane-ops = 13.7M wave-instrs
// -> 11.8us VALU-pipe theoretical; measured 24.5us kernel = 66% issue rate
// = m07's measured practical scalar-FMA ceiling (103/157 TF). DS broadcast
// 12.8us overlapped. Screens (r18-r20) all net-negative: argmin's per-value
// comparison cost is irreducible and the exact scan already folds it best.
#pragma clang fp contract(off)

constexpr int KCODES = 2048;   // EMBEDDING_LENGTH
constexpr int CDIM   = 4;      // EMBEDDING_DIM
constexpr int KSPLIT = 16;     // one k-chunk per wave (16 waves/block)
constexpr int KCHUNK = KCODES / KSPLIT;  // 128 codes per wave
constexpr int RPT    = 4;      // rows per lane
constexpr int ROWSPB = 64 * RPT;         // 256 rows per block
constexpr int TPB    = 64 * KSPLIT;      // 1024 threads; 1 block/CU

__device__ __forceinline__ float min3f(float a, float b, float c) {
    float d; asm("v_min3_f32 %0, %1, %2, %3" : "=v"(d) : "v"(a), "v"(b), "v"(c)); return d;
}
__device__ __forceinline__ float sumsq(float4 e) {
    // np.sum(e*e, -1): ascending unfused mul-add (n<8 scalar loop)
    return ((e.x * e.x + e.y * e.y) + e.z * e.z) + e.w * e.w;
}

__global__ __launch_bounds__(TPB, 4) void vq_fused(
    const float* __restrict__ x,
    const float* __restrict__ emb,
    int* __restrict__ out,
    int N)
{
    // 40 KB carved: sE (32K, e'=-2e) | sS (8K, sums). skey (34K) reuses base.
    __shared__ char smem[40960];
    float4* sE = reinterpret_cast<float4*>(smem);            // [KCODES]
    float4* sS = reinterpret_cast<float4*>(smem + 32768);    // [KCODES/4]

    const float4* __restrict__ embf4 = reinterpret_cast<const float4*>(emb);
    const int t = threadIdx.x;

    for (int i = t; i < KCODES; i += TPB) {
        float4 e = embf4[i];
        sE[i] = make_float4(-2.0f * e.x, -2.0f * e.y, -2.0f * e.z, -2.0f * e.w);
    }
    for (int q = t; q < KCODES / 4; q += TPB) {
        float4 e0 = embf4[4 * q],     e1 = embf4[4 * q + 1];
        float4 e2 = embf4[4 * q + 2], e3 = embf4[4 * q + 3];
        sS[q] = make_float4(sumsq(e0), sumsq(e1), sumsq(e2), sumsq(e3));
    }
    __syncthreads();

    const int lane = t & 63;
    const int wid   = __builtin_amdgcn_readfirstlane(t >> 6);  // r6 lesson
    const int kbase = wid * KCHUNK;
    const int qbase = kbase >> 2;
    const int nbase = blockIdx.x * ROWSPB + lane;

    float x0[RPT], x1[RPT], x2c[RPT], x3[RPT], xs[RPT];
    float dmin[RPT];
    int   bg[RPT];
    #pragma unroll
    for (int r = 0; r < RPT; ++r) {
        const int n = nbase + r * 64;
        float4 xv = (n < N) ? reinterpret_cast<const float4*>(x)[n]
                            : make_float4(0.f, 0.f, 0.f, 0.f);
        x0[r] = xv.x; x1[r] = xv.y; x2c[r] = xv.z; x3[r] = xv.w;
        xs[r] = ((xv.x * xv.x + xv.y * xv.y) + xv.z * xv.z) + xv.w * xv.w;
        dmin[r] = HUGE_VALF; bg[r] = 0;
    }

    // 6 scalar VALU per code + 1 min3 per 2 codes + 2 tracking per group.
    #pragma unroll 2
    for (int g = 0; g < KCHUNK / 8; ++g) {   // 16 groups x 8 codes
        const int k0 = kbase + (g << 3);
        const float4 e0 = sE[k0 + 0], e1 = sE[k0 + 1];
        const float4 e2 = sE[k0 + 2], e3 = sE[k0 + 3];
        const float4 e4 = sE[k0 + 4], e5 = sE[k0 + 5];
        const float4 e6 = sE[k0 + 6], e7 = sE[k0 + 7];
        const float4 sA = sS[qbase + 2 * g];
        const float4 sB = sS[qbase + 2 * g + 1];

        #pragma unroll
        for (int r = 0; r < RPT; ++r) {
            const float a0 = x0[r], a1 = x1[r], a2 = x2c[r], a3 = x3[r];
            const float xq = xs[r];
            const float prev = dmin[r];

            #define VQ_D(EV, SV, OUTV)                                   \
                do {                                                     \
                    float dt = a0 * EV.x;                                \
                    dt = __builtin_fmaf(a1, EV.y, dt);                   \
                    dt = __builtin_fmaf(a2, EV.z, dt);                   \
                    dt = __builtin_fmaf(a3, EV.w, dt);                   \
                    OUTV = (xq + dt) + SV;                               \
                } while (0)

            float d0, d1, d2, d3, d4, d5, d6, d7;
            VQ_D(e0, sA.x, d0); VQ_D(e1, sA.y, d1);
            VQ_D(e2, sA.z, d2); VQ_D(e3, sA.w, d3);
            VQ_D(e4, sB.x, d4); VQ_D(e5, sB.y, d5);
            VQ_D(e6, sB.z, d6); VQ_D(e7, sB.w, d7);
            #undef VQ_D

            float m = min3f(dmin[r], d0, d1);
            m = min3f(m, d2, d3);
            m = min3f(m, d4, d5);
            m = min3f(m, d6, d7);
            bg[r] = (m < prev) ? g : bg[r];   // strict <: earliest group ties
            dmin[r] = m;
        }
    }

    // ---- resolution: recompute the 8 winning codes per row from LDS with
    // the identical scalar chain; first bitwise match wins (np.argmin).
    unsigned long long key[RPT];
    #pragma unroll
    for (int r = 0; r < RPT; ++r) {
        const int k0 = kbase + (bg[r] << 3);
        const float a0 = x0[r], a1 = x1[r], a2 = x2c[r], a3 = x3[r];
        const float xq = xs[r];
        int idx = 0x7fffffff;
        #pragma unroll
        for (int h = 0; h < 2; ++h) {
            const float4 sv = sS[(k0 >> 2) + h];
            const float ss[4] = {sv.x, sv.y, sv.z, sv.w};
            #pragma unroll
            for (int j = 0; j < 4; ++j) {
                const int k = k0 + 4 * h + j;
                const float4 e = sE[k];
                float dt = a0 * e.x;
                dt = __builtin_fmaf(a1, e.y, dt);
                dt = __builtin_fmaf(a2, e.z, dt);
                dt = __builtin_fmaf(a3, e.w, dt);
                const float d = (xq + dt) + ss[j];
                idx = min(idx, (d == dmin[r]) ? k : 0x7fffffff);
            }
        }
        // d >= 0 for this data: float bits order-isomorphic as u32; low bits
        // break exact cross-wave ties toward the smaller index.
        key[r] = ((unsigned long long)__float_as_uint(dmin[r]) << 32)
                 | (unsigned)idx;
    }

    // ---- cross-wave reduce: reuse smem (256 x 17 u64 = 34 KB <= 40 KB) ----
    __syncthreads();
    unsigned long long* skey = reinterpret_cast<unsigned long long*>(smem);
    #pragma unroll
    for (int r = 0; r < RPT; ++r)
        skey[(r * 64 + lane) * (KSPLIT + 1) + wid] = key[r];
    __syncthreads();

    if (t < ROWSPB) {
        const int rn = blockIdx.x * ROWSPB + t;
        if (rn < N) {
            unsigned long long k = skey[t * (KSPLIT + 1)];
            #pragma unroll
            for (int s = 1; s < KSPLIT; ++s) {
                unsigned long long v = skey[t * (KSPLIT + 1) + s];
                if (v < k) k = v;
            }
            out[rn] = (int)(unsigned)(k & 0xFFFFFFFFull);
        }
    }
}

extern "C" void kernel_launch(void* const* d_in, const int* in_sizes, int n_in,
                              void* d_out, int out_size, void* d_ws, size_t ws_size,
                              hipStream_t stream) {
    const float* x   = (const float*)d_in[0];   // [16,64,64,4] -> [N,4]
    const float* emb = (const float*)d_in[1];   // [2048,4]
    int* out = (int*)d_out;                     // [N] int32
    const int N = in_sizes[0] / CDIM;           // 65536

    vq_fused<<<(N + ROWSPB - 1) / ROWSPB, TPB, 0, stream>>>(x, emb, out, N);
}